// Round 10
// baseline (198.487 us; speedup 1.0000x reference)
//
#include <hip/hip_runtime.h>
#include <hip/hip_bf16.h>
#include <math.h>

#define HID 128
#define NH 8
#define DH 16

typedef __bf16 bf16x8 __attribute__((ext_vector_type(8)));
typedef __bf16 bf16x4 __attribute__((ext_vector_type(4)));
typedef float  f32x4  __attribute__((ext_vector_type(4)));

// ---------------------------------------------------------------------------
// Kernel 1 (prep): rowptr binary-search + W -> bf16 cast + bias384.
// Wq/Wk/Wv natural-K; Wo K-dim head-major-permuted (consumes ob head-major).
// ---------------------------------------------------------------------------
__global__ void prep_kernel(const int* __restrict__ row, int* __restrict__ row_ptr,
                            int N_, int E_,
                            const float* __restrict__ Wq, const float* __restrict__ Wk,
                            const float* __restrict__ Wv, const float* __restrict__ Wo,
                            const float* __restrict__ bq, const float* __restrict__ bk,
                            const float* __restrict__ bv,
                            __bf16* __restrict__ Whi, float* __restrict__ bias384) {
    int idx = blockIdx.x * blockDim.x + threadIdx.x;
    if (idx < 4 * 16384) {
        int j = idx >> 14;
        int rem = idx & 16383;
        float x;
        if (j < 3) {
            const float* W = (j == 0) ? Wq : (j == 1) ? Wk : Wv;
            x = W[rem];
        } else {
            int o  = rem >> 7;
            int kp = rem & 127;                      // head-major K index
            int kk = ((kp & 15) << 3) | (kp >> 4);   // reference channel
            x = Wo[o * 128 + kk];
        }
        Whi[idx] = (__bf16)x;
    }
    if (idx <= N_) {
        int lo = 0, hi = E_;
        while (lo < hi) {
            int mid = (lo + hi) >> 1;
            if (row[mid] < idx) lo = mid + 1; else hi = mid;
        }
        row_ptr[idx] = lo;
    }
    if (idx < 384) {
        int j = idx >> 7;
        int pcol = idx & 127;                       // head-major col within proj
        int o = ((pcol & 15) << 3) | (pcol >> 4);   // original W row
        const float* b = (j == 0) ? bq : (j == 1) ? bk : bv;
        bias384[idx] = b[o];
    }
}

// ---------------------------------------------------------------------------
// Kernel 2: QKV projection, single-term bf16 MFMA, direct stores.
// Grid (M/64, 2): by = head-major col half of each of q,k,v -> 192 fused
// cols/block, 4 waves x 48 cols (3 frags).  A cast to bf16 at staging,
// XOR-swizzled 16 KB LDS.  Per k-step: 3 W loads, 4 ds_read_b128, 12 MFMA.
// q,k,v each bf16 [N][128] head-major; epilogue = direct 2B stores in 32B
// segments (no LDS transpose, no extra barriers).
// ---------------------------------------------------------------------------
__global__ __launch_bounds__(256)
void qkv_mfma_kernel(const float* __restrict__ h, int M,
                     const __bf16* __restrict__ Whi,
                     const float* __restrict__ bias384,
                     __bf16* __restrict__ q, __bf16* __restrict__ k,
                     __bf16* __restrict__ v) {
    __shared__ __bf16 As[64 * 128];         // 16 KB
    int tid  = threadIdx.x;
    int wv   = tid >> 6;
    int lane = tid & 63;
    int r    = lane & 15;
    int kg   = lane >> 4;
    int m0   = blockIdx.x * 64;
    int by   = blockIdx.y;                  // col half

    // ---- stage A: coalesced 32B reads, bf16 cast, swizzled 16B slots ----
    #pragma unroll
    for (int it = 0; it < 4; ++it) {
        int flat = it * 256 + tid;          // 16B-slot task 0..1023
        int row  = flat >> 4;               // 0..63
        int s    = flat & 15;               // LDS slot
        int g    = s ^ (row & 7);           // global slot (involution)
        int grow = m0 + row; if (grow > M - 1) grow = M - 1;
        const float* src = &h[(size_t)grow * 128 + g * 8];
        float4 x0 = *(const float4*)src;
        float4 x1 = *(const float4*)(src + 4);
        float xs[8] = {x0.x, x0.y, x0.z, x0.w, x1.x, x1.y, x1.z, x1.w};
        bf16x8 hv8;
        #pragma unroll
        for (int e = 0; e < 8; ++e) hv8[e] = (__bf16)xs[e];
        *(bf16x8*)&As[row * 128 + s * 8] = hv8;
    }
    __syncthreads();

    f32x4 acc[3][4];
    #pragma unroll
    for (int cf = 0; cf < 3; ++cf)
        #pragma unroll
        for (int rf = 0; rf < 4; ++rf)
            acc[cf][rf] = (f32x4){0.f, 0.f, 0.f, 0.f};

    int wrow[3], jseg[3], pcb[3];
    #pragma unroll
    for (int cf = 0; cf < 3; ++cf) {
        int fb   = wv * 48 + cf * 16;       // fragment base within 192
        int seg  = fb >> 6;                 // 0=q 1=k 2=v
        int pcol = by * 64 + (fb & 63) + r; // head-major col within proj
        int o    = ((pcol & 15) << 3) | (pcol >> 4);
        wrow[cf] = (seg * 128 + o) * 128;
        jseg[cf] = seg;
        pcb[cf]  = pcol;
    }

    #pragma unroll
    for (int t = 0; t < 4; ++t) {
        int k0   = t * 32 + kg * 8;
        int slot = t * 4 + kg;
        bf16x8 bh[3];
        #pragma unroll
        for (int cf = 0; cf < 3; ++cf)
            bh[cf] = *(const bf16x8*)&Whi[wrow[cf] + k0];
        bf16x8 ah[4];
        #pragma unroll
        for (int rf = 0; rf < 4; ++rf) {
            int row = rf * 16 + r;
            int s2  = slot ^ (r & 7);
            ah[rf] = *(bf16x8*)&As[row * 128 + s2 * 8];
        }
        #pragma unroll
        for (int cf = 0; cf < 3; ++cf)
            #pragma unroll
            for (int rf = 0; rf < 4; ++rf)
                acc[cf][rf] = __builtin_amdgcn_mfma_f32_16x16x32_bf16(ah[rf], bh[cf], acc[cf][rf], 0, 0, 0);
    }

    // ---- epilogue: direct bf16 stores (32B segments per fragment row) ----
    int orow = kg * 4;
    #pragma unroll
    for (int cf = 0; cf < 3; ++cf) {
        int j    = jseg[cf];
        int pcol = pcb[cf];
        __bf16* dst = (j == 0) ? q : (j == 1) ? k : v;
        float b  = bias384[j * 128 + pcol];
        #pragma unroll
        for (int rf = 0; rf < 4; ++rf) {
            #pragma unroll
            for (int e = 0; e < 4; ++e) {
                int mg = m0 + rf * 16 + orow + e;
                if (mg < M) dst[(size_t)mg * 128 + pcol] = (__bf16)(acc[cf][rf][e] + b);
            }
        }
    }
}

// ---------------------------------------------------------------------------
// Kernel 3: fused SDDMM + online segment-softmax + SPMM.
// One wave per node; unified masked loop, 8 edges/iter (4 per 32-lane half),
// clamped indices + -INF masking, half-uniform merge guard.  k,v separate
// bf16 buffers (two dwordx2 gathers per edge).  Output bf16 head-major.
// ---------------------------------------------------------------------------
__device__ __forceinline__ float blo(unsigned u) { return __uint_as_float(u << 16); }
__device__ __forceinline__ float bhi(unsigned u) { return __uint_as_float(u & 0xffff0000u); }

__global__ __launch_bounds__(256)
void edge_attn_kernel(const int* __restrict__ row_ptr, const int* __restrict__ col,
                      const __bf16* __restrict__ q, const __bf16* __restrict__ kb,
                      const __bf16* __restrict__ vb,
                      __bf16* __restrict__ ob, int N_) {
    int wave = threadIdx.x >> 6;
    int lane = threadIdx.x & 63;
    int node = blockIdx.x * 4 + wave;
    if (node >= N_) return;
    int sl   = lane & 31;
    int half = lane >> 5;

    uint2 qu = *(const uint2*)&q[(size_t)node * 128 + sl * 4];
    float qx = blo(qu.x), qy = bhi(qu.x), qz = blo(qu.y), qw = bhi(qu.y);

    int e0 = row_ptr[node];
    int e1 = row_ptr[node + 1];

    float m = -INFINITY, z = 0.f;
    float4 acc = make_float4(0.f, 0.f, 0.f, 0.f);

    auto score = [&](uint2 u) {
        float p = qx * blo(u.x) + qy * bhi(u.x) +
                  qz * blo(u.y) + qw * bhi(u.y);
        p += __shfl_xor(p, 1);
        p += __shfl_xor(p, 2);
        return p * 0.25f;                       // 1/sqrt(DH)
    };

    for (int eb = e0; eb < e1; eb += 8) {
        int ea  = eb + half * 4;
        bool b0 = ea     < e1, b1 = ea + 1 < e1, b2 = ea + 2 < e1, b3 = ea + 3 < e1;
        int i0 = b0 ? ea     : e1 - 1;
        int i1 = b1 ? ea + 1 : e1 - 1;
        int i2 = b2 ? ea + 2 : e1 - 1;
        int i3 = b3 ? ea + 3 : e1 - 1;
        int c0 = col[i0], c1 = col[i1], c2 = col[i2], c3 = col[i3];
        uint2 k0 = *(const uint2*)(kb + (size_t)c0 * 128 + sl * 4);
        uint2 k1 = *(const uint2*)(kb + (size_t)c1 * 128 + sl * 4);
        uint2 k2 = *(const uint2*)(kb + (size_t)c2 * 128 + sl * 4);
        uint2 k3 = *(const uint2*)(kb + (size_t)c3 * 128 + sl * 4);
        uint2 v0 = *(const uint2*)(vb + (size_t)c0 * 128 + sl * 4);
        uint2 v1 = *(const uint2*)(vb + (size_t)c1 * 128 + sl * 4);
        uint2 v2 = *(const uint2*)(vb + (size_t)c2 * 128 + sl * 4);
        uint2 v3 = *(const uint2*)(vb + (size_t)c3 * 128 + sl * 4);
        float s0 = b0 ? score(k0) : -INFINITY;
        float s1 = b1 ? score(k1) : -INFINITY;
        float s2 = b2 ? score(k2) : -INFINITY;
        float s3 = b3 ? score(k3) : -INFINITY;
        float m03 = fmaxf(fmaxf(s0, s1), fmaxf(s2, s3));
        if (m03 > -INFINITY) {                  // half-uniform branch
            float w0 = __expf(s0 - m03), w1 = __expf(s1 - m03);
            float w2 = __expf(s2 - m03), w3 = __expf(s3 - m03);
            float zl = (w0 + w1) + (w2 + w3);
            float lx = w0 * blo(v0.x) + w1 * blo(v1.x) + w2 * blo(v2.x) + w3 * blo(v3.x);
            float ly = w0 * bhi(v0.x) + w1 * bhi(v1.x) + w2 * bhi(v2.x) + w3 * bhi(v3.x);
            float lz = w0 * blo(v0.y) + w1 * blo(v1.y) + w2 * blo(v2.y) + w3 * blo(v3.y);
            float lw = w0 * bhi(v0.y) + w1 * bhi(v1.y) + w2 * bhi(v2.y) + w3 * bhi(v3.y);
            float mn = fmaxf(m, m03);
            float a1 = __expf(m - mn);          // m=-inf -> 0
            float a2 = __expf(m03 - mn);
            z = z * a1 + zl * a2;
            acc.x = acc.x * a1 + lx * a2;
            acc.y = acc.y * a1 + ly * a2;
            acc.z = acc.z * a1 + lz * a2;
            acc.w = acc.w * a1 + lw * a2;
            m = mn;
        }
    }

    // merge the two halves (lane pairs with lane^32, same sl)
    float m2 = __shfl_xor(m, 32);
    float z2 = __shfl_xor(z, 32);
    float ax = __shfl_xor(acc.x, 32);
    float ay = __shfl_xor(acc.y, 32);
    float az = __shfl_xor(acc.z, 32);
    float aw = __shfl_xor(acc.w, 32);
    float mm = fmaxf(m, m2);
    if (mm > -INFINITY) {
        float a1 = __expf(m - mm);
        float a2 = __expf(m2 - mm);
        z = z * a1 + z2 * a2;
        acc.x = acc.x * a1 + ax * a2;
        acc.y = acc.y * a1 + ay * a2;
        acc.z = acc.z * a1 + az * a2;
        acc.w = acc.w * a1 + aw * a2;
    }

    if (half == 0) {
        float inv = (z > 0.f) ? 1.0f / z : 0.f;
        bf16x4 hv4;
        hv4[0] = (__bf16)(acc.x * inv);
        hv4[1] = (__bf16)(acc.y * inv);
        hv4[2] = (__bf16)(acc.z * inv);
        hv4[3] = (__bf16)(acc.w * inv);
        *(bf16x4*)&ob[(size_t)node * 128 + sl * 4] = hv4;   // head-major
    }
}

// ---------------------------------------------------------------------------
// Kernel 4: output projection, single-term bf16 MFMA.  A = ob bf16
// head-major; Wo K-permuted at prep.  Grid (M/64, 2); 4 waves x 16 cols.
// Per k-step: 1 W load, 4 ds_read_b128, 4 MFMA.  16 KB LDS.
// ---------------------------------------------------------------------------
__global__ __launch_bounds__(256)
void outproj_mfma_kernel(const __bf16* __restrict__ A_g, int M,
                         const __bf16* __restrict__ Whi,
                         const float* __restrict__ bo, float* __restrict__ C) {
    __shared__ __bf16 As[64 * 128];
    int tid  = threadIdx.x;
    int wv   = tid >> 6;
    int lane = tid & 63;
    int r    = lane & 15;
    int kg   = lane >> 4;
    int m0   = blockIdx.x * 64;
    int by   = blockIdx.y;
    int col  = by * 64 + wv * 16 + r;       // output column (natural)

    #pragma unroll
    for (int it = 0; it < 4; ++it) {
        int flat = it * 256 + tid;
        int row  = flat >> 4;
        int s    = flat & 15;
        int g    = s ^ (row & 7);
        int grow = m0 + row; if (grow > M - 1) grow = M - 1;
        *(bf16x8*)&As[row * 128 + s * 8] = *(const bf16x8*)&A_g[(size_t)grow * 128 + g * 8];
    }
    __syncthreads();

    f32x4 acc[4];
    #pragma unroll
    for (int rf = 0; rf < 4; ++rf) acc[rf] = (f32x4){0.f, 0.f, 0.f, 0.f};

    int wrow = col * 128;
    #pragma unroll
    for (int t = 0; t < 4; ++t) {
        int k0   = t * 32 + kg * 8;
        int slot = t * 4 + kg;
        bf16x8 bh = *(const bf16x8*)&Whi[wrow + k0];
        bf16x8 ah[4];
        #pragma unroll
        for (int rf = 0; rf < 4; ++rf) {
            int row = rf * 16 + r;
            int s2  = slot ^ (r & 7);
            ah[rf] = *(bf16x8*)&As[row * 128 + s2 * 8];
        }
        #pragma unroll
        for (int rf = 0; rf < 4; ++rf)
            acc[rf] = __builtin_amdgcn_mfma_f32_16x16x32_bf16(ah[rf], bh, acc[rf], 0, 0, 0);
    }

    float b = bo[col];
    #pragma unroll
    for (int rf = 0; rf < 4; ++rf) {
        #pragma unroll
        for (int e = 0; e < 4; ++e) {
            int mg = m0 + rf * 16 + kg * 4 + e;
            if (mg < M) C[(size_t)mg * 128 + col] = acc[rf][e] + b;
        }
    }
}

// ---------------------------------------------------------------------------
extern "C" void kernel_launch(void* const* d_in, const int* in_sizes, int n_in,
                              void* d_out, int out_size, void* d_ws, size_t ws_size,
                              hipStream_t stream) {
    const float* h  = (const float*)d_in[0];
    const int* row  = (const int*)d_in[1];
    const int* col  = (const int*)d_in[2];
    const float* Wq = (const float*)d_in[3];
    const float* bq = (const float*)d_in[4];
    const float* Wk = (const float*)d_in[5];
    const float* bk = (const float*)d_in[6];
    const float* Wv = (const float*)d_in[7];
    const float* bv = (const float*)d_in[8];
    const float* Wo = (const float*)d_in[9];
    const float* bo = (const float*)d_in[10];
    float* out = (float*)d_out;

    int N_ = in_sizes[0] / HID;   // 50000
    int E_ = in_sizes[1];         // 800000

    char* ws = (char*)d_ws;
    size_t off = 0;
    auto alloc = [&](size_t bytes) {
        void* p = (void*)(ws + off);
        off = (off + bytes + 255) & ~(size_t)255;
        return p;
    };
    int*    row_ptr = (int*)   alloc((size_t)(N_ + 1) * sizeof(int));
    __bf16* qb      = (__bf16*)alloc((size_t)N_ * 128 * sizeof(__bf16));
    __bf16* kvk     = (__bf16*)alloc((size_t)N_ * 128 * sizeof(__bf16));
    __bf16* kvv     = (__bf16*)alloc((size_t)N_ * 128 * sizeof(__bf16));
    __bf16* obb     = (__bf16*)alloc((size_t)N_ * 128 * sizeof(__bf16));
    __bf16* Whi     = (__bf16*)alloc((size_t)4 * 16384 * sizeof(__bf16));
    float*  bias384 = (float*) alloc(384 * sizeof(float));
    (void)ws_size;

    prep_kernel<<<256, 256, 0, stream>>>(row, row_ptr, N_, E_,
                                         Wq, Wk, Wv, Wo, bq, bk, bv,
                                         Whi, bias384);
    qkv_mfma_kernel<<<dim3((N_ + 63) / 64, 2), 256, 0, stream>>>(
        h, N_, Whi, bias384, qb, kvk, kvv);
    edge_attn_kernel<<<(N_ + 3) / 4, 256, 0, stream>>>(row_ptr, col, qb, kvk, kvv, obb, N_);
    outproj_mfma_kernel<<<dim3((N_ + 63) / 64, 2), 256, 0, stream>>>(
        obb, N_, Whi + 3 * 16384, bo, out);
}